// Round 14
// baseline (366.088 us; speedup 1.0000x reference)
//
#include <hip/hip_runtime.h>

// ---------------------------------------------------------------------------
// GraphSAGE 3-layer forward.
//   prep (gcur init + weight frags + bf16 x-plane, one kernel)
//   -> CSR build (capacity-padded coarse bucket; bucketB self-scans cbase)
//   -> per-layer: aggregate(mean, quarter-wave/node, 4-deep MLP, bf16 plane)
//      + MFMA sage GEMM (weights hi/lo, double-buffered global_load_lds
//        staging overlapped with MFMA, 1 barrier/tile) + L2norm + relu
//   -> layer 3 fuses the final linear (Wlin via LDS z-tile, direct fp32 out).
// NOTES:
//  - sage keeps 128 VGPR resident B-fragments -> no min-waves launch bound
//    (R8: VGPR cap -> spills -> 3x HBM traffic).
//  - aggregate is fabric-bound (~3 TB/s random gather, R10/R11) - leave it.
//  - staging: global_load_lds w/ pre-swizzled SOURCE + linear LDS dest
//    (rule #21); next tile's loads issued BEFORE current tile's MFMAs so the
//    psum barrier's vmcnt drain lands after the MFMA phase (T3 minimum).
// ---------------------------------------------------------------------------

typedef __bf16 bf16x8 __attribute__((ext_vector_type(8)));
typedef float  f32x4  __attribute__((ext_vector_type(4)));

#define MFMA16(a, b, c) __builtin_amdgcn_mfma_f32_16x16x32_bf16((a), (b), (c), 0, 0, 0)

__device__ __forceinline__ unsigned rne_bf16(float f) {
  unsigned u = __float_as_uint(f);
  unsigned r = u + 0x7FFFu + ((u >> 16) & 1u);
  return r >> 16;
}

__device__ __forceinline__ float bf_lo(unsigned u) { return __uint_as_float(u << 16); }
__device__ __forceinline__ float bf_hi(unsigned u) { return __uint_as_float(u & 0xFFFF0000u); }

// async 16B global -> LDS (linear dest: wave-uniform base + lane*16)
__device__ __forceinline__ void gload_lds16(const void* g, void* l) {
  __builtin_amdgcn_global_load_lds(
      (const __attribute__((address_space(1))) unsigned int*)g,
      (__attribute__((address_space(3))) unsigned int*)l, 16, 0, 0);
}

// ---------------- prep: gcur init + wfrag + wlin frag + x->bf16 ------------
__global__ __launch_bounds__(256) void prep_k(
    const float* __restrict__ x, const float* __restrict__ Wl,
    const float* __restrict__ Wr, const float* __restrict__ Wlin,
    uint2* __restrict__ planeA, unsigned short* __restrict__ wfrag,
    unsigned short* __restrict__ wlf, int* __restrict__ gcur,
    int cap, int n4) {
  const int b = blockIdx.x;
  const int tid = threadIdx.x;
  if (b == 0) {
    if (tid < 128) gcur[tid] = tid * cap;
    return;
  }
  if (b <= 96) {
    int id = (b - 1) * 256 + tid;
    int l = id & 63;
    int c = (id >> 6) & 7;
    int t = (id >> 9) & 7;
    int p = (id >> 12) & 1;
    int layer = id >> 13;
    int col = t * 16 + (l & 15);
    int kbase = c * 32 + (l >> 4) * 8;
    unsigned short* dst = wfrag + (size_t)layer * 65536 +
                          ((((size_t)p * 8 + t) * 8 + c) * 64 + l) * 8;
#pragma unroll
    for (int j = 0; j < 8; ++j) {
      int k = kbase + j;
      float w = (k < 128) ? Wl[layer * 16384 + col * 128 + k]
                          : Wr[layer * 16384 + col * 128 + (k - 128)];
      unsigned h = rne_bf16(w);
      unsigned o;
      if (p == 0) o = h;
      else o = rne_bf16(w - __uint_as_float(h << 16));
      dst[j] = (unsigned short)o;
    }
    return;
  }
  if (b == 97) {
    for (int id = tid; id < 3 * 4 * 64; id += 256) {
      int l = id & 63;
      int c = (id >> 6) & 3;
      int t = id >> 8;
      int col = t * 16 + (l & 15);
      int kbase = c * 32 + (l >> 4) * 8;
      unsigned short* dst = wlf + (size_t)id * 8;
#pragma unroll
      for (int j = 0; j < 8; ++j) {
        float w = (col < 40) ? Wlin[col * 128 + kbase + j] : 0.f;
        dst[j] = (unsigned short)rne_bf16(w);
      }
    }
    return;
  }
  int i = (b - 98) * 256 + tid;
  if (i >= n4) return;
  float4 f = ((const float4*)x)[i];
  uint2 o;
  o.x = rne_bf16(f.x) | (rne_bf16(f.y) << 16);
  o.y = rne_bf16(f.z) | (rne_bf16(f.w) << 16);
  planeA[i] = o;
}

// ---------------- CSR build ----------------
// pack = src | ((dst & 1023) << 17); requires N < 2^17, N/1024 <= 128.

__global__ __launch_bounds__(256) void bucketA_k(
    const int* __restrict__ src, const int* __restrict__ dst,
    int* __restrict__ gcur, unsigned* __restrict__ coarse, int E, int nc) {
  __shared__ int hist[128];
  __shared__ int sd[128];
  __shared__ int lpos[128];
  __shared__ int gbase[128];
  __shared__ unsigned stage[2048];
  __shared__ unsigned char sbuck[2048];

  const int tid = threadIdx.x;
  const int e0 = blockIdx.x * 2048;

  if (tid < 128) hist[tid] = 0;
  __syncthreads();

  int bv[8], pk[8];
#pragma unroll
  for (int j = 0; j < 8; ++j) {
    int e = e0 + j * 256 + tid;
    bv[j] = -1;
    if (e < E) {
      int s = src[e], d = dst[e];
      bv[j] = d >> 10;
      pk[j] = s | ((d & 1023) << 17);
      atomicAdd(&hist[bv[j]], 1);
    }
  }
  __syncthreads();

  if (tid < 128) sd[tid] = hist[tid];
  __syncthreads();
  for (int off = 1; off < 128; off <<= 1) {
    int t = 0;
    if (tid < 128 && tid >= off) t = sd[tid - off];
    __syncthreads();
    if (tid < 128) sd[tid] += t;
    __syncthreads();
  }
  if (tid < 128) {
    int excl = sd[tid] - hist[tid];
    lpos[tid] = excl;
    gbase[tid] = (tid < nc && hist[tid] > 0) ? atomicAdd(&gcur[tid], hist[tid]) : 0;
  }
  __syncthreads();

#pragma unroll
  for (int j = 0; j < 8; ++j) {
    if (bv[j] >= 0) {
      int slot = atomicAdd(&lpos[bv[j]], 1);
      stage[slot] = (unsigned)pk[j];
      sbuck[slot] = (unsigned char)bv[j];
    }
  }
  __syncthreads();

  const int total = sd[127];
  for (int i = tid; i < total; i += 256) {
    int b = sbuck[i];
    int excl = sd[b] - hist[b];
    coarse[gbase[b] + (i - excl)] = stage[i];
  }
}

__global__ __launch_bounds__(256) void bucketB_k(
    const int* __restrict__ gcur, const unsigned* __restrict__ coarse, int cap,
    int* __restrict__ esrc, int* __restrict__ offsets,
    float* __restrict__ inv_cnt, int n, int nc) {
  __shared__ int hcnt[1024];
  __shared__ int cur[1024];
  __shared__ int sd[256];
  __shared__ int sh_gdst;

  const int tid = threadIdx.x;
  const int b = blockIdx.x;
  const int base = b * 1024;
  const int nn = (n - base < 1024) ? (n - base) : 1024;
  const int wbeg = b * cap;
  const int wend = gcur[b];

  if (tid < 128) {
    int v = (tid < nc) ? (gcur[tid] - tid * cap) : 0;
    sd[tid] = v;
  }
  __syncthreads();
  for (int off = 1; off < 128; off <<= 1) {
    int u = 0;
    if (tid < 128 && tid >= off) u = sd[tid - off];
    __syncthreads();
    if (tid < 128) sd[tid] += u;
    __syncthreads();
  }
  if (tid == b) sh_gdst = sd[tid] - (wend - wbeg);
  for (int j = tid; j < 1024; j += 256) hcnt[j] = 0;
  __syncthreads();
  const int gdst = sh_gdst;

  for (int idx = wbeg + tid; idx < wend; idx += 256)
    atomicAdd(&hcnt[coarse[idx] >> 17], 1);
  __syncthreads();

  int b0 = hcnt[tid * 4], b1 = hcnt[tid * 4 + 1];
  int b2 = hcnt[tid * 4 + 2], b3 = hcnt[tid * 4 + 3];
  int tot = b0 + b1 + b2 + b3;
  sd[tid] = tot;
  __syncthreads();
  for (int off = 1; off < 256; off <<= 1) {
    int u = (tid >= off) ? sd[tid - off] : 0;
    __syncthreads();
    sd[tid] += u;
    __syncthreads();
  }
  int excl = gdst + sd[tid] - tot;
  cur[tid * 4]     = excl;
  cur[tid * 4 + 1] = excl + b0;
  cur[tid * 4 + 2] = excl + b0 + b1;
  cur[tid * 4 + 3] = excl + b0 + b1 + b2;
  __syncthreads();

  for (int j = tid; j < nn; j += 256) {
    offsets[base + j] = cur[j];
    int c = hcnt[j] > 1 ? hcnt[j] : 1;
    inv_cnt[base + j] = 1.0f / (float)c;
  }
  if (tid == 0 && base + nn >= n) offsets[n] = gdst + (wend - wbeg);
  __syncthreads();

  for (int idx = wbeg + tid; idx < wend; idx += 256) {
    unsigned p = coarse[idx];
    int pos = atomicAdd(&cur[p >> 17], 1);
    esrc[pos] = (int)(p & 0x1FFFFu);
  }
}

// ---------------- aggregation: quarter-wave (16 lanes) per node ------------
__global__ void aggregate_k(const unsigned short* __restrict__ zb,
                            const int* __restrict__ offsets,
                            const int* __restrict__ esrc,
                            const float* __restrict__ inv_cnt,
                            unsigned short* __restrict__ aggh, int n) {
  int node = (blockIdx.x * 256 + threadIdx.x) >> 4;
  int l16 = threadIdx.x & 15;
  if (node >= n) return;
  int beg = offsets[node], end = offsets[node + 1];
  float a0 = 0.f, a1 = 0.f, a2 = 0.f, a3 = 0.f;
  float a4 = 0.f, a5 = 0.f, a6 = 0.f, a7 = 0.f;
  int t = beg;
  for (; t + 4 <= end; t += 4) {
    int s0 = esrc[t], s1 = esrc[t + 1], s2 = esrc[t + 2], s3 = esrc[t + 3];
    uint4 d0 = *(const uint4*)(zb + (size_t)s0 * 128 + l16 * 8);
    uint4 d1 = *(const uint4*)(zb + (size_t)s1 * 128 + l16 * 8);
    uint4 d2 = *(const uint4*)(zb + (size_t)s2 * 128 + l16 * 8);
    uint4 d3 = *(const uint4*)(zb + (size_t)s3 * 128 + l16 * 8);
    a0 += bf_lo(d0.x); a1 += bf_hi(d0.x); a2 += bf_lo(d0.y); a3 += bf_hi(d0.y);
    a4 += bf_lo(d0.z); a5 += bf_hi(d0.z); a6 += bf_lo(d0.w); a7 += bf_hi(d0.w);
    a0 += bf_lo(d1.x); a1 += bf_hi(d1.x); a2 += bf_lo(d1.y); a3 += bf_hi(d1.y);
    a4 += bf_lo(d1.z); a5 += bf_hi(d1.z); a6 += bf_lo(d1.w); a7 += bf_hi(d1.w);
    a0 += bf_lo(d2.x); a1 += bf_hi(d2.x); a2 += bf_lo(d2.y); a3 += bf_hi(d2.y);
    a4 += bf_lo(d2.z); a5 += bf_hi(d2.z); a6 += bf_lo(d2.w); a7 += bf_hi(d2.w);
    a0 += bf_lo(d3.x); a1 += bf_hi(d3.x); a2 += bf_lo(d3.y); a3 += bf_hi(d3.y);
    a4 += bf_lo(d3.z); a5 += bf_hi(d3.z); a6 += bf_lo(d3.w); a7 += bf_hi(d3.w);
  }
  for (; t + 2 <= end; t += 2) {
    int s0 = esrc[t], s1 = esrc[t + 1];
    uint4 d0 = *(const uint4*)(zb + (size_t)s0 * 128 + l16 * 8);
    uint4 d1 = *(const uint4*)(zb + (size_t)s1 * 128 + l16 * 8);
    a0 += bf_lo(d0.x); a1 += bf_hi(d0.x); a2 += bf_lo(d0.y); a3 += bf_hi(d0.y);
    a4 += bf_lo(d0.z); a5 += bf_hi(d0.z); a6 += bf_lo(d0.w); a7 += bf_hi(d0.w);
    a0 += bf_lo(d1.x); a1 += bf_hi(d1.x); a2 += bf_lo(d1.y); a3 += bf_hi(d1.y);
    a4 += bf_lo(d1.z); a5 += bf_hi(d1.z); a6 += bf_lo(d1.w); a7 += bf_hi(d1.w);
  }
  if (t < end) {
    int s0 = esrc[t];
    uint4 d0 = *(const uint4*)(zb + (size_t)s0 * 128 + l16 * 8);
    a0 += bf_lo(d0.x); a1 += bf_hi(d0.x); a2 += bf_lo(d0.y); a3 += bf_hi(d0.y);
    a4 += bf_lo(d0.z); a5 += bf_hi(d0.z); a6 += bf_lo(d0.w); a7 += bf_hi(d0.w);
  }
  float ic = inv_cnt[node];
  uint4 hv;
  hv.x = rne_bf16(a0 * ic) | (rne_bf16(a1 * ic) << 16);
  hv.y = rne_bf16(a2 * ic) | (rne_bf16(a3 * ic) << 16);
  hv.z = rne_bf16(a4 * ic) | (rne_bf16(a5 * ic) << 16);
  hv.w = rne_bf16(a6 * ic) | (rne_bf16(a7 * ic) << 16);
  *(uint4*)(aggh + (size_t)node * 128 + l16 * 8) = hv;
}

// ---------------- SAGE layer via MFMA, double-buffered pipeline ------------
// LDS image per buffer: 32 rows x 512B, row r = [agg(256B)|z(256B)], 16B
// blocks swizzled by b^=(r&7) via pre-swizzled SOURCE address.
// Per tile: issue next-tile gload_lds -> 64 MFMA (both s) -> psum write ->
// ONE barrier (publishes psum, releases cur buf, drains next loads) ->
// epilogue. psum parity-double-buffered.
template <bool FUSE>
__global__ __launch_bounds__(256) void sage_layer_mfma_k(
    const unsigned short* __restrict__ zb, const unsigned short* __restrict__ aggh,
    const unsigned short* __restrict__ wf, const float* __restrict__ bl,
    unsigned short* __restrict__ out_bf,
    const unsigned short* __restrict__ wlf, const float* __restrict__ blin,
    float* __restrict__ fout, int n, int ntiles) {
  __shared__ unsigned short Ah_s[2][32 * 256];           // 2 x 16 KB
  __shared__ unsigned short Zt_s[FUSE ? 32 * 128 : 8];   // 8 KB only if FUSE
  __shared__ float psum[2][2][4][16];                    // [parity][s][wv][row]

  const int lane = threadIdx.x & 63;
  const int wv = threadIdx.x >> 6;
  const int g = lane >> 4;
  const int rl = lane & 15;

  const bf16x8* wfv = (const bf16x8*)wf;
  const int t0 = wv * 2, t1 = wv * 2 + 1;
  bf16x8 Bh0[8], Bh1[8], Bl0[8], Bl1[8];
#pragma unroll
  for (int c = 0; c < 8; ++c) {
    Bh0[c] = wfv[((0 * 8 + t0) * 8 + c) * 64 + lane];
    Bh1[c] = wfv[((0 * 8 + t1) * 8 + c) * 64 + lane];
    Bl0[c] = wfv[((1 * 8 + t0) * 8 + c) * 64 + lane];
    Bl1[c] = wfv[((1 * 8 + t1) * 8 + c) * 64 + lane];
  }
  const float b0 = bl[t0 * 16 + rl];
  const float b1 = bl[t1 * 16 + rl];

  char* pZt = (char*)Zt_s;
  const bf16x8* wlfv = (const bf16x8*)wlf;

  // staging geometry: wave-issue wq -> LDS bytes wq*1024; lanes 0-15 agg row
  // 2wq, 16-31 z row 2wq, 32-47 agg row 2wq+1, 48-63 z row 2wq+1.
  const int rsub = lane >> 5;
  const int hlf = (lane >> 4) & 1;
  const int b16 = lane & 15;

  int tile = blockIdx.x;
  if (tile >= ntiles) return;

  // prologue: stage first tile into buf 0
  {
    const int v0 = tile * 32;
#pragma unroll
    for (int q = 0; q < 4; ++q) {
      int wq = wv * 4 + q;
      int r = wq * 2 + rsub;
      int v = v0 + r; v = (v < n) ? v : (n - 1);
      int sblk = b16 ^ (r & 7);
      gload_lds16((hlf ? zb : aggh) + (size_t)v * 128 + sblk * 8,
                  (char*)Ah_s[0] + wq * 1024);
    }
  }
  __syncthreads();

  int cur = 0, par = 0;
  while (tile < ntiles) {
    const int next = tile + gridDim.x;
    // ---- issue next tile's loads into the other buffer (flies during MFMA)
    if (next < ntiles) {
      const int v0n = next * 32;
#pragma unroll
      for (int q = 0; q < 4; ++q) {
        int wq = wv * 4 + q;
        int r = wq * 2 + rsub;
        int v = v0n + r; v = (v < n) ? v : (n - 1);
        int sblk = b16 ^ (r & 7);
        gload_lds16((hlf ? zb : aggh) + (size_t)v * 128 + sblk * 8,
                    (char*)Ah_s[cur ^ 1] + wq * 1024);
      }
    }

    const int v0 = tile * 32;
    char* pAh = (char*)Ah_s[cur];

    // ---- 64 MFMA: both node-subtiles
    f32x4 a00 = {0.f,0.f,0.f,0.f}, a10 = {0.f,0.f,0.f,0.f};
    f32x4 a01 = {0.f,0.f,0.f,0.f}, a11 = {0.f,0.f,0.f,0.f};
    {
      const int swz = (rl & 7) << 4;
      const int row0 = rl * 512;
      const int row1 = (16 + rl) * 512;
#pragma unroll
      for (int c = 0; c < 8; ++c) {
        int o0 = (row0 + c * 64 + g * 16) ^ swz;
        int o1 = (row1 + c * 64 + g * 16) ^ swz;
        bf16x8 ah0 = *(const bf16x8*)(pAh + o0);
        bf16x8 ah1 = *(const bf16x8*)(pAh + o1);
        a00 = MFMA16(ah0, Bh0[c], a00); a10 = MFMA16(ah0, Bh1[c], a10);
        a00 = MFMA16(ah0, Bl0[c], a00); a10 = MFMA16(ah0, Bl1[c], a10);
        a01 = MFMA16(ah1, Bh0[c], a01); a11 = MFMA16(ah1, Bh1[c], a11);
        a01 = MFMA16(ah1, Bl0[c], a01); a11 = MFMA16(ah1, Bl1[c], a11);
      }
    }

    // ---- bias + partial sumsq for both s, publish psum
    {
      float pr0[4], pr1[4];
#pragma unroll
      for (int j = 0; j < 4; ++j) {
        a00[j] += b0; a10[j] += b1;
        a01[j] += b0; a11[j] += b1;
        pr0[j] = a00[j]*a00[j] + a10[j]*a10[j];
        pr1[j] = a01[j]*a01[j] + a11[j]*a11[j];
      }
#pragma unroll
      for (int m = 1; m < 16; m <<= 1) {
#pragma unroll
        for (int j = 0; j < 4; ++j) {
          pr0[j] += __shfl_xor(pr0[j], m);
          pr1[j] += __shfl_xor(pr1[j], m);
        }
      }
      if (rl == 0) {
#pragma unroll
        for (int j = 0; j < 4; ++j) {
          psum[par][0][wv][g * 4 + j] = pr0[j];
          psum[par][1][wv][g * 4 + j] = pr1[j];
        }
      }
    }
    __syncthreads();   // psum ready; cur buf released; next-tile loads drained

    // ---- epilogue both s
#pragma unroll
    for (int s = 0; s < 2; ++s) {
      f32x4& A0 = s ? a01 : a00;
      f32x4& A1 = s ? a11 : a10;
#pragma unroll
      for (int j = 0; j < 4; ++j) {
        int row16 = g * 4 + j;
        float tot = psum[par][s][0][row16] + psum[par][s][1][row16] +
                    psum[par][s][2][row16] + psum[par][s][3][row16];
        float inv = 1.0f / fmaxf(sqrtf(tot), 1e-12f);
        int v = v0 + s * 16 + row16;
        float o0 = fmaxf(A0[j] * inv, 0.f);
        float o1 = fmaxf(A1[j] * inv, 0.f);
        unsigned short q0 = (unsigned short)rne_bf16(o0);
        unsigned short q1 = (unsigned short)rne_bf16(o1);
        if (!FUSE) {
          if (v < n) {
            out_bf[(size_t)v * 128 + t0 * 16 + rl] = q0;
            out_bf[(size_t)v * 128 + t1 * 16 + rl] = q1;
          }
        } else {
          int rloc = s * 16 + row16;
          int sw = (rloc & 7) << 4;
          *(unsigned short*)(pZt + ((rloc * 256 + (t0 * 16 + rl) * 2) ^ sw)) = q0;
          *(unsigned short*)(pZt + ((rloc * 256 + (t1 * 16 + rl) * 2) ^ sw)) = q1;
        }
      }
    }

    if (FUSE) {
      __syncthreads();   // Zt tile complete
      for (int job = wv; job < 6; job += 4) {
        int s = job / 3, t = job % 3;
        f32x4 acc = {0.f, 0.f, 0.f, 0.f};
        const int rowz = s * 16 + rl;
        const int swzz = (rowz & 7) << 4;
#pragma unroll
        for (int c = 0; c < 4; ++c) {
          bf16x8 a = *(const bf16x8*)(pZt + ((rowz * 256 + c * 64 + g * 16) ^ swzz));
          bf16x8 bw = wlfv[(t * 4 + c) * 64 + lane];
          acc = MFMA16(a, bw, acc);
        }
        int col = t * 16 + rl;
        if (col < 40) {
          float bb = blin[col];
#pragma unroll
          for (int j = 0; j < 4; ++j) {
            int v = v0 + s * 16 + g * 4 + j;
            if (v < n) fout[(size_t)v * 40 + col] = acc[j] + bb;
          }
        }
      }
      __syncthreads();   // Zt released before next iteration's writes
    }

    tile = next; cur ^= 1; par ^= 1;
  }
}

// ---------------- launch ----------------

extern "C" void kernel_launch(void* const* d_in, const int* in_sizes, int n_in,
                              void* d_out, int out_size, void* d_ws, size_t ws_size,
                              hipStream_t stream) {
  const float* x    = (const float*)d_in[0];
  const int*   ei   = (const int*)d_in[1];
  const float* Wl   = (const float*)d_in[2];
  const float* bl   = (const float*)d_in[3];
  const float* Wr   = (const float*)d_in[4];
  const float* Wlin = (const float*)d_in[5];
  const float* blin = (const float*)d_in[6];

  const int N = in_sizes[0] / 128;
  const int E = in_sizes[1] / 2;
  const int D = 128;
  const int NC = (N + 1023) >> 10;
  const int cap = (E + NC - 1) / NC + 4096;   // padded coarse-bucket capacity

  const int* src = ei;
  const int* dstp = ei + E;

  // workspace layout
  unsigned short* planeA = (unsigned short*)d_ws;            // N*128 bf16
  unsigned short* planeB = planeA + (size_t)N * D;           // N*128 bf16
  unsigned short* aggh   = planeB + (size_t)N * D;           // N*128 bf16 (agg)
  float* inv_cnt = (float*)(aggh + (size_t)N * D);           // N
  unsigned short* wlf = (unsigned short*)(inv_cnt + N);      // 6144 ushorts
  unsigned short* Wfrag = wlf + 6144;                        // 3*65536
  int*   offsets = (int*)(Wfrag + 3 * 65536);                // N+1
  int*   esrc    = offsets + N + 1;                          // E
  unsigned* coarse = (unsigned*)(esrc + E);                  // NC*cap
  int*   gcur    = (int*)(coarse + (size_t)NC * cap);        // 128

  // prep (gcur init + weight frags + bf16 x plane)
  const int n4 = N * 32;
  prep_k<<<98 + (n4 + 255) / 256, 256, 0, stream>>>(
      x, Wl, Wr, Wlin, (uint2*)planeA, Wfrag, wlf, gcur, cap, n4);

  // CSR build
  bucketA_k<<<(E + 2047) / 2048, 256, 0, stream>>>(src, dstp, gcur, coarse, E, NC);
  bucketB_k<<<NC, 256, 0, stream>>>(gcur, coarse, cap, esrc, offsets, inv_cnt, N, NC);

  const int aggGrid = (N * 16 + 255) / 256;   // 16 threads per node
  const int ntiles = (N + 31) / 32;
  const int sageGrid = 768;                   // 3 blocks/CU resident, ~4 tiles each

  // layer 1
  aggregate_k<<<aggGrid, 256, 0, stream>>>(planeA, offsets, esrc, inv_cnt, aggh, N);
  sage_layer_mfma_k<false><<<sageGrid, 256, 0, stream>>>(
      planeA, aggh, Wfrag + 0 * 65536, bl + 0 * D, planeB, wlf, blin, nullptr, N, ntiles);
  // layer 2
  aggregate_k<<<aggGrid, 256, 0, stream>>>(planeB, offsets, esrc, inv_cnt, aggh, N);
  sage_layer_mfma_k<false><<<sageGrid, 256, 0, stream>>>(
      planeB, aggh, Wfrag + 1 * 65536, bl + 1 * D, planeA, wlf, blin, nullptr, N, ntiles);
  // layer 3 + fused final linear
  aggregate_k<<<aggGrid, 256, 0, stream>>>(planeA, offsets, esrc, inv_cnt, aggh, N);
  sage_layer_mfma_k<true><<<sageGrid, 256, 0, stream>>>(
      planeA, aggh, Wfrag + 2 * 65536, bl + 2 * D, nullptr, wlf, blin,
      (float*)d_out, N, ntiles);
}

// Round 15
// 349.882 us; speedup vs baseline: 1.0463x; 1.0463x over previous
//
#include <hip/hip_runtime.h>

// ---------------------------------------------------------------------------
// GraphSAGE 3-layer forward.
//   prep (gcur init + weight frags + bf16 x-plane, one kernel)
//   -> CSR build (capacity-padded coarse bucket; bucketB self-scans cbase)
//   -> per-layer: aggregate(mean, quarter-wave/node, 4-deep MLP, bf16 plane)
//      + MFMA sage GEMM (agg-half: weights hi/lo; z-half: weights hi only)
//        with global_load_lds staging + L2norm + relu
//   -> layer 3 fuses the final linear (Wlin via LDS z-tile, direct fp32 out).
// NOTES:
//  - sage keeps ~96 VGPR resident B-fragments -> no min-waves launch bound
//    (R8: VGPR cap -> spills -> 3x HBM traffic).
//  - aggregate is fabric-bound (~3 TB/s random gather, R10/R11) - leave it.
//  - NO double-buffered staging (R14: compiler drains vmcnt before ds_read,
//    serializing "overlapped" loads -> regression). Single-buffer, R13 form.
//  - z-half weight-lo dropped: z input already bf16 (same-order error) - R15.
// ---------------------------------------------------------------------------

typedef __bf16 bf16x8 __attribute__((ext_vector_type(8)));
typedef float  f32x4  __attribute__((ext_vector_type(4)));

#define MFMA16(a, b, c) __builtin_amdgcn_mfma_f32_16x16x32_bf16((a), (b), (c), 0, 0, 0)

__device__ __forceinline__ unsigned rne_bf16(float f) {
  unsigned u = __float_as_uint(f);
  unsigned r = u + 0x7FFFu + ((u >> 16) & 1u);
  return r >> 16;
}

__device__ __forceinline__ float bf_lo(unsigned u) { return __uint_as_float(u << 16); }
__device__ __forceinline__ float bf_hi(unsigned u) { return __uint_as_float(u & 0xFFFF0000u); }

// async 16B global -> LDS (linear dest: wave-uniform base + lane*16)
__device__ __forceinline__ void gload_lds16(const void* g, void* l) {
  __builtin_amdgcn_global_load_lds(
      (const __attribute__((address_space(1))) unsigned int*)g,
      (__attribute__((address_space(3))) unsigned int*)l, 16, 0, 0);
}

// ---------------- prep: gcur init + wfrag + wlin frag + x->bf16 ------------
__global__ __launch_bounds__(256) void prep_k(
    const float* __restrict__ x, const float* __restrict__ Wl,
    const float* __restrict__ Wr, const float* __restrict__ Wlin,
    uint2* __restrict__ planeA, unsigned short* __restrict__ wfrag,
    unsigned short* __restrict__ wlf, int* __restrict__ gcur,
    int cap, int n4) {
  const int b = blockIdx.x;
  const int tid = threadIdx.x;
  if (b == 0) {
    if (tid < 128) gcur[tid] = tid * cap;
    return;
  }
  if (b <= 96) {
    int id = (b - 1) * 256 + tid;
    int l = id & 63;
    int c = (id >> 6) & 7;
    int t = (id >> 9) & 7;
    int p = (id >> 12) & 1;
    int layer = id >> 13;
    int col = t * 16 + (l & 15);
    int kbase = c * 32 + (l >> 4) * 8;
    unsigned short* dst = wfrag + (size_t)layer * 65536 +
                          ((((size_t)p * 8 + t) * 8 + c) * 64 + l) * 8;
#pragma unroll
    for (int j = 0; j < 8; ++j) {
      int k = kbase + j;
      float w = (k < 128) ? Wl[layer * 16384 + col * 128 + k]
                          : Wr[layer * 16384 + col * 128 + (k - 128)];
      unsigned h = rne_bf16(w);
      unsigned o;
      if (p == 0) o = h;
      else o = rne_bf16(w - __uint_as_float(h << 16));
      dst[j] = (unsigned short)o;
    }
    return;
  }
  if (b == 97) {
    for (int id = tid; id < 3 * 4 * 64; id += 256) {
      int l = id & 63;
      int c = (id >> 6) & 3;
      int t = id >> 8;
      int col = t * 16 + (l & 15);
      int kbase = c * 32 + (l >> 4) * 8;
      unsigned short* dst = wlf + (size_t)id * 8;
#pragma unroll
      for (int j = 0; j < 8; ++j) {
        float w = (col < 40) ? Wlin[col * 128 + kbase + j] : 0.f;
        dst[j] = (unsigned short)rne_bf16(w);
      }
    }
    return;
  }
  int i = (b - 98) * 256 + tid;
  if (i >= n4) return;
  float4 f = ((const float4*)x)[i];
  uint2 o;
  o.x = rne_bf16(f.x) | (rne_bf16(f.y) << 16);
  o.y = rne_bf16(f.z) | (rne_bf16(f.w) << 16);
  planeA[i] = o;
}

// ---------------- CSR build ----------------
// pack = src | ((dst & 1023) << 17); requires N < 2^17, N/1024 <= 128.

__global__ __launch_bounds__(256) void bucketA_k(
    const int* __restrict__ src, const int* __restrict__ dst,
    int* __restrict__ gcur, unsigned* __restrict__ coarse, int E, int nc) {
  __shared__ int hist[128];
  __shared__ int sd[128];
  __shared__ int lpos[128];
  __shared__ int gbase[128];
  __shared__ unsigned stage[2048];
  __shared__ unsigned char sbuck[2048];

  const int tid = threadIdx.x;
  const int e0 = blockIdx.x * 2048;

  if (tid < 128) hist[tid] = 0;
  __syncthreads();

  int bv[8], pk[8];
#pragma unroll
  for (int j = 0; j < 8; ++j) {
    int e = e0 + j * 256 + tid;
    bv[j] = -1;
    if (e < E) {
      int s = src[e], d = dst[e];
      bv[j] = d >> 10;
      pk[j] = s | ((d & 1023) << 17);
      atomicAdd(&hist[bv[j]], 1);
    }
  }
  __syncthreads();

  if (tid < 128) sd[tid] = hist[tid];
  __syncthreads();
  for (int off = 1; off < 128; off <<= 1) {
    int t = 0;
    if (tid < 128 && tid >= off) t = sd[tid - off];
    __syncthreads();
    if (tid < 128) sd[tid] += t;
    __syncthreads();
  }
  if (tid < 128) {
    int excl = sd[tid] - hist[tid];
    lpos[tid] = excl;
    gbase[tid] = (tid < nc && hist[tid] > 0) ? atomicAdd(&gcur[tid], hist[tid]) : 0;
  }
  __syncthreads();

#pragma unroll
  for (int j = 0; j < 8; ++j) {
    if (bv[j] >= 0) {
      int slot = atomicAdd(&lpos[bv[j]], 1);
      stage[slot] = (unsigned)pk[j];
      sbuck[slot] = (unsigned char)bv[j];
    }
  }
  __syncthreads();

  const int total = sd[127];
  for (int i = tid; i < total; i += 256) {
    int b = sbuck[i];
    int excl = sd[b] - hist[b];
    coarse[gbase[b] + (i - excl)] = stage[i];
  }
}

__global__ __launch_bounds__(256) void bucketB_k(
    const int* __restrict__ gcur, const unsigned* __restrict__ coarse, int cap,
    int* __restrict__ esrc, int* __restrict__ offsets,
    float* __restrict__ inv_cnt, int n, int nc) {
  __shared__ int hcnt[1024];
  __shared__ int cur[1024];
  __shared__ int sd[256];
  __shared__ int sh_gdst;

  const int tid = threadIdx.x;
  const int b = blockIdx.x;
  const int base = b * 1024;
  const int nn = (n - base < 1024) ? (n - base) : 1024;
  const int wbeg = b * cap;
  const int wend = gcur[b];

  if (tid < 128) {
    int v = (tid < nc) ? (gcur[tid] - tid * cap) : 0;
    sd[tid] = v;
  }
  __syncthreads();
  for (int off = 1; off < 128; off <<= 1) {
    int u = 0;
    if (tid < 128 && tid >= off) u = sd[tid - off];
    __syncthreads();
    if (tid < 128) sd[tid] += u;
    __syncthreads();
  }
  if (tid == b) sh_gdst = sd[tid] - (wend - wbeg);
  for (int j = tid; j < 1024; j += 256) hcnt[j] = 0;
  __syncthreads();
  const int gdst = sh_gdst;

  for (int idx = wbeg + tid; idx < wend; idx += 256)
    atomicAdd(&hcnt[coarse[idx] >> 17], 1);
  __syncthreads();

  int b0 = hcnt[tid * 4], b1 = hcnt[tid * 4 + 1];
  int b2 = hcnt[tid * 4 + 2], b3 = hcnt[tid * 4 + 3];
  int tot = b0 + b1 + b2 + b3;
  sd[tid] = tot;
  __syncthreads();
  for (int off = 1; off < 256; off <<= 1) {
    int u = (tid >= off) ? sd[tid - off] : 0;
    __syncthreads();
    sd[tid] += u;
    __syncthreads();
  }
  int excl = gdst + sd[tid] - tot;
  cur[tid * 4]     = excl;
  cur[tid * 4 + 1] = excl + b0;
  cur[tid * 4 + 2] = excl + b0 + b1;
  cur[tid * 4 + 3] = excl + b0 + b1 + b2;
  __syncthreads();

  for (int j = tid; j < nn; j += 256) {
    offsets[base + j] = cur[j];
    int c = hcnt[j] > 1 ? hcnt[j] : 1;
    inv_cnt[base + j] = 1.0f / (float)c;
  }
  if (tid == 0 && base + nn >= n) offsets[n] = gdst + (wend - wbeg);
  __syncthreads();

  for (int idx = wbeg + tid; idx < wend; idx += 256) {
    unsigned p = coarse[idx];
    int pos = atomicAdd(&cur[p >> 17], 1);
    esrc[pos] = (int)(p & 0x1FFFFu);
  }
}

// ---------------- aggregation: quarter-wave (16 lanes) per node ------------
__global__ void aggregate_k(const unsigned short* __restrict__ zb,
                            const int* __restrict__ offsets,
                            const int* __restrict__ esrc,
                            const float* __restrict__ inv_cnt,
                            unsigned short* __restrict__ aggh, int n) {
  int node = (blockIdx.x * 256 + threadIdx.x) >> 4;
  int l16 = threadIdx.x & 15;
  if (node >= n) return;
  int beg = offsets[node], end = offsets[node + 1];
  float a0 = 0.f, a1 = 0.f, a2 = 0.f, a3 = 0.f;
  float a4 = 0.f, a5 = 0.f, a6 = 0.f, a7 = 0.f;
  int t = beg;
  for (; t + 4 <= end; t += 4) {
    int s0 = esrc[t], s1 = esrc[t + 1], s2 = esrc[t + 2], s3 = esrc[t + 3];
    uint4 d0 = *(const uint4*)(zb + (size_t)s0 * 128 + l16 * 8);
    uint4 d1 = *(const uint4*)(zb + (size_t)s1 * 128 + l16 * 8);
    uint4 d2 = *(const uint4*)(zb + (size_t)s2 * 128 + l16 * 8);
    uint4 d3 = *(const uint4*)(zb + (size_t)s3 * 128 + l16 * 8);
    a0 += bf_lo(d0.x); a1 += bf_hi(d0.x); a2 += bf_lo(d0.y); a3 += bf_hi(d0.y);
    a4 += bf_lo(d0.z); a5 += bf_hi(d0.z); a6 += bf_lo(d0.w); a7 += bf_hi(d0.w);
    a0 += bf_lo(d1.x); a1 += bf_hi(d1.x); a2 += bf_lo(d1.y); a3 += bf_hi(d1.y);
    a4 += bf_lo(d1.z); a5 += bf_hi(d1.z); a6 += bf_lo(d1.w); a7 += bf_hi(d1.w);
    a0 += bf_lo(d2.x); a1 += bf_hi(d2.x); a2 += bf_lo(d2.y); a3 += bf_hi(d2.y);
    a4 += bf_lo(d2.z); a5 += bf_hi(d2.z); a6 += bf_lo(d2.w); a7 += bf_hi(d2.w);
    a0 += bf_lo(d3.x); a1 += bf_hi(d3.x); a2 += bf_lo(d3.y); a3 += bf_hi(d3.y);
    a4 += bf_lo(d3.z); a5 += bf_hi(d3.z); a6 += bf_lo(d3.w); a7 += bf_hi(d3.w);
  }
  for (; t + 2 <= end; t += 2) {
    int s0 = esrc[t], s1 = esrc[t + 1];
    uint4 d0 = *(const uint4*)(zb + (size_t)s0 * 128 + l16 * 8);
    uint4 d1 = *(const uint4*)(zb + (size_t)s1 * 128 + l16 * 8);
    a0 += bf_lo(d0.x); a1 += bf_hi(d0.x); a2 += bf_lo(d0.y); a3 += bf_hi(d0.y);
    a4 += bf_lo(d0.z); a5 += bf_hi(d0.z); a6 += bf_lo(d0.w); a7 += bf_hi(d0.w);
    a0 += bf_lo(d1.x); a1 += bf_hi(d1.x); a2 += bf_lo(d1.y); a3 += bf_hi(d1.y);
    a4 += bf_lo(d1.z); a5 += bf_hi(d1.z); a6 += bf_lo(d1.w); a7 += bf_hi(d1.w);
  }
  if (t < end) {
    int s0 = esrc[t];
    uint4 d0 = *(const uint4*)(zb + (size_t)s0 * 128 + l16 * 8);
    a0 += bf_lo(d0.x); a1 += bf_hi(d0.x); a2 += bf_lo(d0.y); a3 += bf_hi(d0.y);
    a4 += bf_lo(d0.z); a5 += bf_hi(d0.z); a6 += bf_lo(d0.w); a7 += bf_hi(d0.w);
  }
  float ic = inv_cnt[node];
  uint4 hv;
  hv.x = rne_bf16(a0 * ic) | (rne_bf16(a1 * ic) << 16);
  hv.y = rne_bf16(a2 * ic) | (rne_bf16(a3 * ic) << 16);
  hv.z = rne_bf16(a4 * ic) | (rne_bf16(a5 * ic) << 16);
  hv.w = rne_bf16(a6 * ic) | (rne_bf16(a7 * ic) << 16);
  *(uint4*)(aggh + (size_t)node * 128 + l16 * 8) = hv;
}

// ---------------- SAGE layer via MFMA (optionally fused final linear) ------
// LDS image: 32 rows x 512B, row r = [agg row (256B, 16B-block-swizzled by
// b^=(r&7)) | z row (same swizzle)]. Staged via global_load_lds: linear LDS
// dest (wave-uniform base + lane*16), swizzle applied to SOURCE address.
// Chunks c=0..3 (agg half): Wl hi+lo. Chunks c=4..7 (z half): Wr hi only
// (z already bf16 -> weight-lo below input noise). 48 MFMA/tile.
template <bool FUSE>
__global__ __launch_bounds__(256) void sage_layer_mfma_k(
    const unsigned short* __restrict__ zb, const unsigned short* __restrict__ aggh,
    const unsigned short* __restrict__ wf, const float* __restrict__ bl,
    unsigned short* __restrict__ out_bf,
    const unsigned short* __restrict__ wlf, const float* __restrict__ blin,
    float* __restrict__ fout, int n, int ntiles) {
  __shared__ unsigned short Ah_s[32 * 256];              // 16 KB
  __shared__ unsigned short Zt_s[FUSE ? 32 * 128 : 8];   // 8 KB only if FUSE
  __shared__ float psum[2][4][16];

  const int lane = threadIdx.x & 63;
  const int wv = threadIdx.x >> 6;
  const int g = lane >> 4;
  const int rl = lane & 15;

  const bf16x8* wfv = (const bf16x8*)wf;
  const int t0 = wv * 2, t1 = wv * 2 + 1;
  bf16x8 Bh0[8], Bh1[8], Bl0[4], Bl1[4];
#pragma unroll
  for (int c = 0; c < 8; ++c) {
    Bh0[c] = wfv[((0 * 8 + t0) * 8 + c) * 64 + lane];
    Bh1[c] = wfv[((0 * 8 + t1) * 8 + c) * 64 + lane];
  }
#pragma unroll
  for (int c = 0; c < 4; ++c) {
    Bl0[c] = wfv[((1 * 8 + t0) * 8 + c) * 64 + lane];
    Bl1[c] = wfv[((1 * 8 + t1) * 8 + c) * 64 + lane];
  }
  const float b0 = bl[t0 * 16 + rl];
  const float b1 = bl[t1 * 16 + rl];

  char* pAh = (char*)Ah_s;
  char* pZt = (char*)Zt_s;
  const bf16x8* wlfv = (const bf16x8*)wlf;

  // staging geometry (per wave-issue wq in [0,16)): LDS bytes wq*1024..+1023,
  // rows 2wq, 2wq+1; lanes 0-15 agg row, 16-31 z row, 32-47 agg r+1, 48-63 z r+1.
  const int rsub = lane >> 5;            // row within pair
  const int hlf = (lane >> 4) & 1;       // 0: agg, 1: z
  const int b16 = lane & 15;             // 16B block within 256B half

  for (int tile = blockIdx.x; tile < ntiles; tile += gridDim.x) {
    const int v0 = tile * 32;

    // ---- stage via global_load_lds (pre-swizzled source, linear LDS dest)
#pragma unroll
    for (int q = 0; q < 4; ++q) {
      int wq = wv * 4 + q;
      int r = wq * 2 + rsub;
      int v = v0 + r; v = (v < n) ? v : (n - 1);
      int sblk = b16 ^ (r & 7);
      const unsigned short* srcp =
          (hlf ? zb : aggh) + (size_t)v * 128 + sblk * 8;
      gload_lds16(srcp, pAh + wq * 1024);
    }
    __syncthreads();

#pragma unroll
    for (int s = 0; s < 2; ++s) {
      f32x4 a0 = {0.f, 0.f, 0.f, 0.f};
      f32x4 a1 = {0.f, 0.f, 0.f, 0.f};
      const int rowH = (s * 16 + rl) * 512;
      const int swz = (rl & 7) << 4;
#pragma unroll
      for (int c = 0; c < 4; ++c) {        // agg half: weights hi+lo
        int offH = (rowH + c * 64 + g * 16) ^ swz;
        bf16x8 ah = *(const bf16x8*)(pAh + offH);
        a0 = MFMA16(ah, Bh0[c], a0); a1 = MFMA16(ah, Bh1[c], a1);
        a0 = MFMA16(ah, Bl0[c], a0); a1 = MFMA16(ah, Bl1[c], a1);
      }
#pragma unroll
      for (int c = 4; c < 8; ++c) {        // z half: weights hi only
        int offH = (rowH + c * 64 + g * 16) ^ swz;
        bf16x8 ah = *(const bf16x8*)(pAh + offH);
        a0 = MFMA16(ah, Bh0[c], a0); a1 = MFMA16(ah, Bh1[c], a1);
      }
      float pr[4];
#pragma unroll
      for (int j = 0; j < 4; ++j) {
        a0[j] += b0; a1[j] += b1;
        pr[j] = a0[j] * a0[j] + a1[j] * a1[j];
      }
#pragma unroll
      for (int m = 1; m < 16; m <<= 1) {
#pragma unroll
        for (int j = 0; j < 4; ++j) pr[j] += __shfl_xor(pr[j], m);
      }
      if (rl == 0) {
#pragma unroll
        for (int j = 0; j < 4; ++j) psum[s][wv][g * 4 + j] = pr[j];
      }
      __syncthreads();
#pragma unroll
      for (int j = 0; j < 4; ++j) {
        int row16 = g * 4 + j;
        float tot = psum[s][0][row16] + psum[s][1][row16] +
                    psum[s][2][row16] + psum[s][3][row16];
        float inv = 1.0f / fmaxf(sqrtf(tot), 1e-12f);
        int v = v0 + s * 16 + row16;
        float o0 = fmaxf(a0[j] * inv, 0.f);
        float o1 = fmaxf(a1[j] * inv, 0.f);
        unsigned short q0 = (unsigned short)rne_bf16(o0);
        unsigned short q1 = (unsigned short)rne_bf16(o1);
        if (!FUSE) {
          if (v < n) {
            out_bf[(size_t)v * 128 + t0 * 16 + rl] = q0;
            out_bf[(size_t)v * 128 + t1 * 16 + rl] = q1;
          }
        } else {
          int rloc = s * 16 + row16;
          int sw = (rloc & 7) << 4;
          *(unsigned short*)(pZt + ((rloc * 256 + (t0 * 16 + rl) * 2) ^ sw)) = q0;
          *(unsigned short*)(pZt + ((rloc * 256 + (t1 * 16 + rl) * 2) ^ sw)) = q1;
        }
      }
    }

    if (FUSE) {
      __syncthreads();
      for (int job = wv; job < 6; job += 4) {
        int s = job / 3, t = job % 3;
        f32x4 acc = {0.f, 0.f, 0.f, 0.f};
        const int rowz = s * 16 + rl;
        const int swzz = (rowz & 7) << 4;
#pragma unroll
        for (int c = 0; c < 4; ++c) {
          bf16x8 a = *(const bf16x8*)(pZt + ((rowz * 256 + c * 64 + g * 16) ^ swzz));
          bf16x8 bw = wlfv[(t * 4 + c) * 64 + lane];
          acc = MFMA16(a, bw, acc);
        }
        int col = t * 16 + rl;
        if (col < 40) {
          float bb = blin[col];
#pragma unroll
          for (int j = 0; j < 4; ++j) {
            int v = v0 + s * 16 + g * 4 + j;
            if (v < n) fout[(size_t)v * 40 + col] = acc[j] + bb;
          }
        }
      }
    }
    __syncthreads();
  }
}

// ---------------- launch ----------------

extern "C" void kernel_launch(void* const* d_in, const int* in_sizes, int n_in,
                              void* d_out, int out_size, void* d_ws, size_t ws_size,
                              hipStream_t stream) {
  const float* x    = (const float*)d_in[0];
  const int*   ei   = (const int*)d_in[1];
  const float* Wl   = (const float*)d_in[2];
  const float* bl   = (const float*)d_in[3];
  const float* Wr   = (const float*)d_in[4];
  const float* Wlin = (const float*)d_in[5];
  const float* blin = (const float*)d_in[6];

  const int N = in_sizes[0] / 128;
  const int E = in_sizes[1] / 2;
  const int D = 128;
  const int NC = (N + 1023) >> 10;
  const int cap = (E + NC - 1) / NC + 4096;   // padded coarse-bucket capacity

  const int* src = ei;
  const int* dstp = ei + E;

  // workspace layout
  unsigned short* planeA = (unsigned short*)d_ws;            // N*128 bf16
  unsigned short* planeB = planeA + (size_t)N * D;           // N*128 bf16
  unsigned short* aggh   = planeB + (size_t)N * D;           // N*128 bf16 (agg)
  float* inv_cnt = (float*)(aggh + (size_t)N * D);           // N
  unsigned short* wlf = (unsigned short*)(inv_cnt + N);      // 6144 ushorts
  unsigned short* Wfrag = wlf + 6144;                        // 3*65536
  int*   offsets = (int*)(Wfrag + 3 * 65536);                // N+1
  int*   esrc    = offsets + N + 1;                          // E
  unsigned* coarse = (unsigned*)(esrc + E);                  // NC*cap
  int*   gcur    = (int*)(coarse + (size_t)NC * cap);        // 128

  // prep (gcur init + weight frags + bf16 x plane)
  const int n4 = N * 32;
  prep_k<<<98 + (n4 + 255) / 256, 256, 0, stream>>>(
      x, Wl, Wr, Wlin, (uint2*)planeA, Wfrag, wlf, gcur, cap, n4);

  // CSR build
  bucketA_k<<<(E + 2047) / 2048, 256, 0, stream>>>(src, dstp, gcur, coarse, E, NC);
  bucketB_k<<<NC, 256, 0, stream>>>(gcur, coarse, cap, esrc, offsets, inv_cnt, N, NC);

  const int aggGrid = (N * 16 + 255) / 256;   // 16 threads per node
  const int ntiles = (N + 31) / 32;
  const int sageGrid = 1024;                  // 4 blocks/CU, grid-stride ~3 tiles

  // layer 1
  aggregate_k<<<aggGrid, 256, 0, stream>>>(planeA, offsets, esrc, inv_cnt, aggh, N);
  sage_layer_mfma_k<false><<<sageGrid, 256, 0, stream>>>(
      planeA, aggh, Wfrag + 0 * 65536, bl + 0 * D, planeB, wlf, blin, nullptr, N, ntiles);
  // layer 2
  aggregate_k<<<aggGrid, 256, 0, stream>>>(planeB, offsets, esrc, inv_cnt, aggh, N);
  sage_layer_mfma_k<false><<<sageGrid, 256, 0, stream>>>(
      planeB, aggh, Wfrag + 1 * 65536, bl + 1 * D, planeA, wlf, blin, nullptr, N, ntiles);
  // layer 3 + fused final linear
  aggregate_k<<<aggGrid, 256, 0, stream>>>(planeA, offsets, esrc, inv_cnt, aggh, N);
  sage_layer_mfma_k<true><<<sageGrid, 256, 0, stream>>>(
      planeA, aggh, Wfrag + 2 * 65536, bl + 2 * D, nullptr, wlf, blin,
      (float*)d_out, N, ntiles);
}

// Round 16
// 348.217 us; speedup vs baseline: 1.0513x; 1.0048x over previous
//
#include <hip/hip_runtime.h>

// ---------------------------------------------------------------------------
// GraphSAGE 3-layer forward.
//   prep (gcur init + weight frags + bf16 x-plane, one kernel)
//   -> CSR build (capacity-padded coarse bucket; bucketB self-scans cbase)
//   -> per-layer: aggregate(mean, quarter-wave/node, 4-deep MLP, bf16 plane)
//      + MFMA sage GEMM (agg-half: weights hi/lo; z-half: hi only) with
//        global_load_lds staging, batched both-subtile MFMA, 2 barriers/tile
//   -> layer 3 fuses the final linear (Wlin via LDS z-tile, direct fp32 out).
// NOTES:
//  - sage keeps ~96 VGPR resident B-fragments -> no min-waves launch bound
//    (R8: VGPR cap -> spills -> 3x HBM traffic).
//  - aggregate is at its structural floor: each XCD L2 refills the whole
//    25.6MB plane per layer (random graph, non-coherent L2s) -> ~58us. Leave.
//  - NO double-buffered staging (R14: compiler drains vmcnt before ds_read).
//  - psum parity-double-buffered; barriers: stage-sync + psum-sync (+Zt if FUSE).
// ---------------------------------------------------------------------------

typedef __bf16 bf16x8 __attribute__((ext_vector_type(8)));
typedef float  f32x4  __attribute__((ext_vector_type(4)));

#define MFMA16(a, b, c) __builtin_amdgcn_mfma_f32_16x16x32_bf16((a), (b), (c), 0, 0, 0)

__device__ __forceinline__ unsigned rne_bf16(float f) {
  unsigned u = __float_as_uint(f);
  unsigned r = u + 0x7FFFu + ((u >> 16) & 1u);
  return r >> 16;
}

__device__ __forceinline__ float bf_lo(unsigned u) { return __uint_as_float(u << 16); }
__device__ __forceinline__ float bf_hi(unsigned u) { return __uint_as_float(u & 0xFFFF0000u); }

// async 16B global -> LDS (linear dest: wave-uniform base + lane*16)
__device__ __forceinline__ void gload_lds16(const void* g, void* l) {
  __builtin_amdgcn_global_load_lds(
      (const __attribute__((address_space(1))) unsigned int*)g,
      (__attribute__((address_space(3))) unsigned int*)l, 16, 0, 0);
}

// ---------------- prep: gcur init + wfrag + wlin frag + x->bf16 ------------
__global__ __launch_bounds__(256) void prep_k(
    const float* __restrict__ x, const float* __restrict__ Wl,
    const float* __restrict__ Wr, const float* __restrict__ Wlin,
    uint2* __restrict__ planeA, unsigned short* __restrict__ wfrag,
    unsigned short* __restrict__ wlf, int* __restrict__ gcur,
    int cap, int n4) {
  const int b = blockIdx.x;
  const int tid = threadIdx.x;
  if (b == 0) {
    if (tid < 128) gcur[tid] = tid * cap;
    return;
  }
  if (b <= 96) {
    int id = (b - 1) * 256 + tid;
    int l = id & 63;
    int c = (id >> 6) & 7;
    int t = (id >> 9) & 7;
    int p = (id >> 12) & 1;
    int layer = id >> 13;
    int col = t * 16 + (l & 15);
    int kbase = c * 32 + (l >> 4) * 8;
    unsigned short* dst = wfrag + (size_t)layer * 65536 +
                          ((((size_t)p * 8 + t) * 8 + c) * 64 + l) * 8;
#pragma unroll
    for (int j = 0; j < 8; ++j) {
      int k = kbase + j;
      float w = (k < 128) ? Wl[layer * 16384 + col * 128 + k]
                          : Wr[layer * 16384 + col * 128 + (k - 128)];
      unsigned h = rne_bf16(w);
      unsigned o;
      if (p == 0) o = h;
      else o = rne_bf16(w - __uint_as_float(h << 16));
      dst[j] = (unsigned short)o;
    }
    return;
  }
  if (b == 97) {
    for (int id = tid; id < 3 * 4 * 64; id += 256) {
      int l = id & 63;
      int c = (id >> 6) & 3;
      int t = id >> 8;
      int col = t * 16 + (l & 15);
      int kbase = c * 32 + (l >> 4) * 8;
      unsigned short* dst = wlf + (size_t)id * 8;
#pragma unroll
      for (int j = 0; j < 8; ++j) {
        float w = (col < 40) ? Wlin[col * 128 + kbase + j] : 0.f;
        dst[j] = (unsigned short)rne_bf16(w);
      }
    }
    return;
  }
  int i = (b - 98) * 256 + tid;
  if (i >= n4) return;
  float4 f = ((const float4*)x)[i];
  uint2 o;
  o.x = rne_bf16(f.x) | (rne_bf16(f.y) << 16);
  o.y = rne_bf16(f.z) | (rne_bf16(f.w) << 16);
  planeA[i] = o;
}

// ---------------- CSR build ----------------
// pack = src | ((dst & 1023) << 17); requires N < 2^17, N/1024 <= 128.

__global__ __launch_bounds__(256) void bucketA_k(
    const int* __restrict__ src, const int* __restrict__ dst,
    int* __restrict__ gcur, unsigned* __restrict__ coarse, int E, int nc) {
  __shared__ int hist[128];
  __shared__ int sd[128];
  __shared__ int lpos[128];
  __shared__ int gbase[128];
  __shared__ unsigned stage[2048];
  __shared__ unsigned char sbuck[2048];

  const int tid = threadIdx.x;
  const int e0 = blockIdx.x * 2048;

  if (tid < 128) hist[tid] = 0;
  __syncthreads();

  int bv[8], pk[8];
#pragma unroll
  for (int j = 0; j < 8; ++j) {
    int e = e0 + j * 256 + tid;
    bv[j] = -1;
    if (e < E) {
      int s = src[e], d = dst[e];
      bv[j] = d >> 10;
      pk[j] = s | ((d & 1023) << 17);
      atomicAdd(&hist[bv[j]], 1);
    }
  }
  __syncthreads();

  if (tid < 128) sd[tid] = hist[tid];
  __syncthreads();
  for (int off = 1; off < 128; off <<= 1) {
    int t = 0;
    if (tid < 128 && tid >= off) t = sd[tid - off];
    __syncthreads();
    if (tid < 128) sd[tid] += t;
    __syncthreads();
  }
  if (tid < 128) {
    int excl = sd[tid] - hist[tid];
    lpos[tid] = excl;
    gbase[tid] = (tid < nc && hist[tid] > 0) ? atomicAdd(&gcur[tid], hist[tid]) : 0;
  }
  __syncthreads();

#pragma unroll
  for (int j = 0; j < 8; ++j) {
    if (bv[j] >= 0) {
      int slot = atomicAdd(&lpos[bv[j]], 1);
      stage[slot] = (unsigned)pk[j];
      sbuck[slot] = (unsigned char)bv[j];
    }
  }
  __syncthreads();

  const int total = sd[127];
  for (int i = tid; i < total; i += 256) {
    int b = sbuck[i];
    int excl = sd[b] - hist[b];
    coarse[gbase[b] + (i - excl)] = stage[i];
  }
}

__global__ __launch_bounds__(256) void bucketB_k(
    const int* __restrict__ gcur, const unsigned* __restrict__ coarse, int cap,
    int* __restrict__ esrc, int* __restrict__ offsets,
    float* __restrict__ inv_cnt, int n, int nc) {
  __shared__ int hcnt[1024];
  __shared__ int cur[1024];
  __shared__ int sd[256];
  __shared__ int sh_gdst;

  const int tid = threadIdx.x;
  const int b = blockIdx.x;
  const int base = b * 1024;
  const int nn = (n - base < 1024) ? (n - base) : 1024;
  const int wbeg = b * cap;
  const int wend = gcur[b];

  if (tid < 128) {
    int v = (tid < nc) ? (gcur[tid] - tid * cap) : 0;
    sd[tid] = v;
  }
  __syncthreads();
  for (int off = 1; off < 128; off <<= 1) {
    int u = 0;
    if (tid < 128 && tid >= off) u = sd[tid - off];
    __syncthreads();
    if (tid < 128) sd[tid] += u;
    __syncthreads();
  }
  if (tid == b) sh_gdst = sd[tid] - (wend - wbeg);
  for (int j = tid; j < 1024; j += 256) hcnt[j] = 0;
  __syncthreads();
  const int gdst = sh_gdst;

  for (int idx = wbeg + tid; idx < wend; idx += 256)
    atomicAdd(&hcnt[coarse[idx] >> 17], 1);
  __syncthreads();

  int b0 = hcnt[tid * 4], b1 = hcnt[tid * 4 + 1];
  int b2 = hcnt[tid * 4 + 2], b3 = hcnt[tid * 4 + 3];
  int tot = b0 + b1 + b2 + b3;
  sd[tid] = tot;
  __syncthreads();
  for (int off = 1; off < 256; off <<= 1) {
    int u = (tid >= off) ? sd[tid - off] : 0;
    __syncthreads();
    sd[tid] += u;
    __syncthreads();
  }
  int excl = gdst + sd[tid] - tot;
  cur[tid * 4]     = excl;
  cur[tid * 4 + 1] = excl + b0;
  cur[tid * 4 + 2] = excl + b0 + b1;
  cur[tid * 4 + 3] = excl + b0 + b1 + b2;
  __syncthreads();

  for (int j = tid; j < nn; j += 256) {
    offsets[base + j] = cur[j];
    int c = hcnt[j] > 1 ? hcnt[j] : 1;
    inv_cnt[base + j] = 1.0f / (float)c;
  }
  if (tid == 0 && base + nn >= n) offsets[n] = gdst + (wend - wbeg);
  __syncthreads();

  for (int idx = wbeg + tid; idx < wend; idx += 256) {
    unsigned p = coarse[idx];
    int pos = atomicAdd(&cur[p >> 17], 1);
    esrc[pos] = (int)(p & 0x1FFFFu);
  }
}

// ---------------- aggregation: quarter-wave (16 lanes) per node ------------
__global__ void aggregate_k(const unsigned short* __restrict__ zb,
                            const int* __restrict__ offsets,
                            const int* __restrict__ esrc,
                            const float* __restrict__ inv_cnt,
                            unsigned short* __restrict__ aggh, int n) {
  int node = (blockIdx.x * 256 + threadIdx.x) >> 4;
  int l16 = threadIdx.x & 15;
  if (node >= n) return;
  int beg = offsets[node], end = offsets[node + 1];
  float a0 = 0.f, a1 = 0.f, a2 = 0.f, a3 = 0.f;
  float a4 = 0.f, a5 = 0.f, a6 = 0.f, a7 = 0.f;
  int t = beg;
  for (; t + 4 <= end; t += 4) {
    int s0 = esrc[t], s1 = esrc[t + 1], s2 = esrc[t + 2], s3 = esrc[t + 3];
    uint4 d0 = *(const uint4*)(zb + (size_t)s0 * 128 + l16 * 8);
    uint4 d1 = *(const uint4*)(zb + (size_t)s1 * 128 + l16 * 8);
    uint4 d2 = *(const uint4*)(zb + (size_t)s2 * 128 + l16 * 8);
    uint4 d3 = *(const uint4*)(zb + (size_t)s3 * 128 + l16 * 8);
    a0 += bf_lo(d0.x); a1 += bf_hi(d0.x); a2 += bf_lo(d0.y); a3 += bf_hi(d0.y);
    a4 += bf_lo(d0.z); a5 += bf_hi(d0.z); a6 += bf_lo(d0.w); a7 += bf_hi(d0.w);
    a0 += bf_lo(d1.x); a1 += bf_hi(d1.x); a2 += bf_lo(d1.y); a3 += bf_hi(d1.y);
    a4 += bf_lo(d1.z); a5 += bf_hi(d1.z); a6 += bf_lo(d1.w); a7 += bf_hi(d1.w);
    a0 += bf_lo(d2.x); a1 += bf_hi(d2.x); a2 += bf_lo(d2.y); a3 += bf_hi(d2.y);
    a4 += bf_lo(d2.z); a5 += bf_hi(d2.z); a6 += bf_lo(d2.w); a7 += bf_hi(d2.w);
    a0 += bf_lo(d3.x); a1 += bf_hi(d3.x); a2 += bf_lo(d3.y); a3 += bf_hi(d3.y);
    a4 += bf_lo(d3.z); a5 += bf_hi(d3.z); a6 += bf_lo(d3.w); a7 += bf_hi(d3.w);
  }
  for (; t + 2 <= end; t += 2) {
    int s0 = esrc[t], s1 = esrc[t + 1];
    uint4 d0 = *(const uint4*)(zb + (size_t)s0 * 128 + l16 * 8);
    uint4 d1 = *(const uint4*)(zb + (size_t)s1 * 128 + l16 * 8);
    a0 += bf_lo(d0.x); a1 += bf_hi(d0.x); a2 += bf_lo(d0.y); a3 += bf_hi(d0.y);
    a4 += bf_lo(d0.z); a5 += bf_hi(d0.z); a6 += bf_lo(d0.w); a7 += bf_hi(d0.w);
    a0 += bf_lo(d1.x); a1 += bf_hi(d1.x); a2 += bf_lo(d1.y); a3 += bf_hi(d1.y);
    a4 += bf_lo(d1.z); a5 += bf_hi(d1.z); a6 += bf_lo(d1.w); a7 += bf_hi(d1.w);
  }
  if (t < end) {
    int s0 = esrc[t];
    uint4 d0 = *(const uint4*)(zb + (size_t)s0 * 128 + l16 * 8);
    a0 += bf_lo(d0.x); a1 += bf_hi(d0.x); a2 += bf_lo(d0.y); a3 += bf_hi(d0.y);
    a4 += bf_lo(d0.z); a5 += bf_hi(d0.z); a6 += bf_lo(d0.w); a7 += bf_hi(d0.w);
  }
  float ic = inv_cnt[node];
  uint4 hv;
  hv.x = rne_bf16(a0 * ic) | (rne_bf16(a1 * ic) << 16);
  hv.y = rne_bf16(a2 * ic) | (rne_bf16(a3 * ic) << 16);
  hv.z = rne_bf16(a4 * ic) | (rne_bf16(a5 * ic) << 16);
  hv.w = rne_bf16(a6 * ic) | (rne_bf16(a7 * ic) << 16);
  *(uint4*)(aggh + (size_t)node * 128 + l16 * 8) = hv;
}

// ---------------- SAGE layer via MFMA (optionally fused final linear) ------
// LDS image: 32 rows x 512B, row r = [agg(256B)|z(256B)], 16B blocks swizzled
// by b^=(r&7) via pre-swizzled SOURCE; linear gload_lds dest (rule #21).
// Per tile: stage -> barrier A -> 48 MFMA both subtiles -> psum[par] write ->
// barrier B -> epilogue (psum read + store). 2 barriers/tile (3 if FUSE).
template <bool FUSE>
__global__ __launch_bounds__(256) void sage_layer_mfma_k(
    const unsigned short* __restrict__ zb, const unsigned short* __restrict__ aggh,
    const unsigned short* __restrict__ wf, const float* __restrict__ bl,
    unsigned short* __restrict__ out_bf,
    const unsigned short* __restrict__ wlf, const float* __restrict__ blin,
    float* __restrict__ fout, int n, int ntiles) {
  __shared__ unsigned short Ah_s[32 * 256];              // 16 KB
  __shared__ unsigned short Zt_s[FUSE ? 32 * 128 : 8];   // 8 KB only if FUSE
  __shared__ float psum[2][2][4][16];                    // [parity][s][wv][row]

  const int lane = threadIdx.x & 63;
  const int wv = threadIdx.x >> 6;
  const int g = lane >> 4;
  const int rl = lane & 15;

  const bf16x8* wfv = (const bf16x8*)wf;
  const int t0 = wv * 2, t1 = wv * 2 + 1;
  bf16x8 Bh0[8], Bh1[8], Bl0[4], Bl1[4];
#pragma unroll
  for (int c = 0; c < 8; ++c) {
    Bh0[c] = wfv[((0 * 8 + t0) * 8 + c) * 64 + lane];
    Bh1[c] = wfv[((0 * 8 + t1) * 8 + c) * 64 + lane];
  }
#pragma unroll
  for (int c = 0; c < 4; ++c) {
    Bl0[c] = wfv[((1 * 8 + t0) * 8 + c) * 64 + lane];
    Bl1[c] = wfv[((1 * 8 + t1) * 8 + c) * 64 + lane];
  }
  const float b0 = bl[t0 * 16 + rl];
  const float b1 = bl[t1 * 16 + rl];

  char* pAh = (char*)Ah_s;
  char* pZt = (char*)Zt_s;
  const bf16x8* wlfv = (const bf16x8*)wlf;

  // staging geometry (per wave-issue wq in [0,16)): LDS bytes wq*1024..+1023,
  // rows 2wq, 2wq+1; lanes 0-15 agg row, 16-31 z row, 32-47 agg r+1, 48-63 z r+1.
  const int rsub = lane >> 5;
  const int hlf = (lane >> 4) & 1;
  const int b16 = lane & 15;

  int par = 0;
  for (int tile = blockIdx.x; tile < ntiles; tile += gridDim.x) {
    const int v0 = tile * 32;

    // ---- stage via global_load_lds (pre-swizzled source, linear LDS dest)
#pragma unroll
    for (int q = 0; q < 4; ++q) {
      int wq = wv * 4 + q;
      int r = wq * 2 + rsub;
      int v = v0 + r; v = (v < n) ? v : (n - 1);
      int sblk = b16 ^ (r & 7);
      const unsigned short* srcp =
          (hlf ? zb : aggh) + (size_t)v * 128 + sblk * 8;
      gload_lds16(srcp, pAh + wq * 1024);
    }
    __syncthreads();   // A: loads drained & visible; prior psum reads done

    // ---- 48 MFMA: both node-subtiles
    f32x4 a00 = {0.f,0.f,0.f,0.f}, a10 = {0.f,0.f,0.f,0.f};
    f32x4 a01 = {0.f,0.f,0.f,0.f}, a11 = {0.f,0.f,0.f,0.f};
    {
      const int swz = (rl & 7) << 4;
      const int row0 = rl * 512;
      const int row1 = (16 + rl) * 512;
#pragma unroll
      for (int c = 0; c < 4; ++c) {          // agg half: weights hi+lo
        int o0 = (row0 + c * 64 + g * 16) ^ swz;
        int o1 = (row1 + c * 64 + g * 16) ^ swz;
        bf16x8 ah0 = *(const bf16x8*)(pAh + o0);
        bf16x8 ah1 = *(const bf16x8*)(pAh + o1);
        a00 = MFMA16(ah0, Bh0[c], a00); a10 = MFMA16(ah0, Bh1[c], a10);
        a00 = MFMA16(ah0, Bl0[c], a00); a10 = MFMA16(ah0, Bl1[c], a10);
        a01 = MFMA16(ah1, Bh0[c], a01); a11 = MFMA16(ah1, Bh1[c], a11);
        a01 = MFMA16(ah1, Bl0[c], a01); a11 = MFMA16(ah1, Bl1[c], a11);
      }
#pragma unroll
      for (int c = 4; c < 8; ++c) {          // z half: weights hi only
        int o0 = (row0 + c * 64 + g * 16) ^ swz;
        int o1 = (row1 + c * 64 + g * 16) ^ swz;
        bf16x8 ah0 = *(const bf16x8*)(pAh + o0);
        bf16x8 ah1 = *(const bf16x8*)(pAh + o1);
        a00 = MFMA16(ah0, Bh0[c], a00); a10 = MFMA16(ah0, Bh1[c], a10);
        a01 = MFMA16(ah1, Bh0[c], a01); a11 = MFMA16(ah1, Bh1[c], a11);
      }
    }

    // ---- bias + partial sumsq both s, publish psum[par]
    {
      float pr0[4], pr1[4];
#pragma unroll
      for (int j = 0; j < 4; ++j) {
        a00[j] += b0; a10[j] += b1;
        a01[j] += b0; a11[j] += b1;
        pr0[j] = a00[j]*a00[j] + a10[j]*a10[j];
        pr1[j] = a01[j]*a01[j] + a11[j]*a11[j];
      }
#pragma unroll
      for (int m = 1; m < 16; m <<= 1) {
#pragma unroll
        for (int j = 0; j < 4; ++j) {
          pr0[j] += __shfl_xor(pr0[j], m);
          pr1[j] += __shfl_xor(pr1[j], m);
        }
      }
      if (rl == 0) {
#pragma unroll
        for (int j = 0; j < 4; ++j) {
          psum[par][0][wv][g * 4 + j] = pr0[j];
          psum[par][1][wv][g * 4 + j] = pr1[j];
        }
      }
    }
    __syncthreads();   // B: psum visible; all Ah ds_reads complete

    // ---- epilogue both s
#pragma unroll
    for (int s = 0; s < 2; ++s) {
      f32x4& A0 = s ? a01 : a00;
      f32x4& A1 = s ? a11 : a10;
#pragma unroll
      for (int j = 0; j < 4; ++j) {
        int row16 = g * 4 + j;
        float tot = psum[par][s][0][row16] + psum[par][s][1][row16] +
                    psum[par][s][2][row16] + psum[par][s][3][row16];
        float inv = 1.0f / fmaxf(sqrtf(tot), 1e-12f);
        int v = v0 + s * 16 + row16;
        float o0 = fmaxf(A0[j] * inv, 0.f);
        float o1 = fmaxf(A1[j] * inv, 0.f);
        unsigned short q0 = (unsigned short)rne_bf16(o0);
        unsigned short q1 = (unsigned short)rne_bf16(o1);
        if (!FUSE) {
          if (v < n) {
            out_bf[(size_t)v * 128 + t0 * 16 + rl] = q0;
            out_bf[(size_t)v * 128 + t1 * 16 + rl] = q1;
          }
        } else {
          int rloc = s * 16 + row16;
          int sw = (rloc & 7) << 4;
          *(unsigned short*)(pZt + ((rloc * 256 + (t0 * 16 + rl) * 2) ^ sw)) = q0;
          *(unsigned short*)(pZt + ((rloc * 256 + (t1 * 16 + rl) * 2) ^ sw)) = q1;
        }
      }
    }

    if (FUSE) {
      __syncthreads();   // C: Zt tile complete
      for (int job = wv; job < 6; job += 4) {
        int s = job / 3, t = job % 3;
        f32x4 acc = {0.f, 0.f, 0.f, 0.f};
        const int rowz = s * 16 + rl;
        const int swzz = (rowz & 7) << 4;
#pragma unroll
        for (int c = 0; c < 4; ++c) {
          bf16x8 a = *(const bf16x8*)(pZt + ((rowz * 256 + c * 64 + g * 16) ^ swzz));
          bf16x8 bw = wlfv[(t * 4 + c) * 64 + lane];
          acc = MFMA16(a, bw, acc);
        }
        int col = t * 16 + rl;
        if (col < 40) {
          float bb = blin[col];
#pragma unroll
          for (int j = 0; j < 4; ++j) {
            int v = v0 + s * 16 + g * 4 + j;
            if (v < n) fout[(size_t)v * 40 + col] = acc[j] + bb;
          }
        }
      }
    }
    par ^= 1;
  }
}

// ---------------- launch ----------------

extern "C" void kernel_launch(void* const* d_in, const int* in_sizes, int n_in,
                              void* d_out, int out_size, void* d_ws, size_t ws_size,
                              hipStream_t stream) {
  const float* x    = (const float*)d_in[0];
  const int*   ei   = (const int*)d_in[1];
  const float* Wl   = (const float*)d_in[2];
  const float* bl   = (const float*)d_in[3];
  const float* Wr   = (const float*)d_in[4];
  const float* Wlin = (const float*)d_in[5];
  const float* blin = (const float*)d_in[6];

  const int N = in_sizes[0] / 128;
  const int E = in_sizes[1] / 2;
  const int D = 128;
  const int NC = (N + 1023) >> 10;
  const int cap = (E + NC - 1) / NC + 4096;   // padded coarse-bucket capacity

  const int* src = ei;
  const int* dstp = ei + E;

  // workspace layout
  unsigned short* planeA = (unsigned short*)d_ws;            // N*128 bf16
  unsigned short* planeB = planeA + (size_t)N * D;           // N*128 bf16
  unsigned short* aggh   = planeB + (size_t)N * D;           // N*128 bf16 (agg)
  float* inv_cnt = (float*)(aggh + (size_t)N * D);           // N
  unsigned short* wlf = (unsigned short*)(inv_cnt + N);      // 6144 ushorts
  unsigned short* Wfrag = wlf + 6144;                        // 3*65536
  int*   offsets = (int*)(Wfrag + 3 * 65536);                // N+1
  int*   esrc    = offsets + N + 1;                          // E
  unsigned* coarse = (unsigned*)(esrc + E);                  // NC*cap
  int*   gcur    = (int*)(coarse + (size_t)NC * cap);        // 128

  // prep (gcur init + weight frags + bf16 x plane)
  const int n4 = N * 32;
  prep_k<<<98 + (n4 + 255) / 256, 256, 0, stream>>>(
      x, Wl, Wr, Wlin, (uint2*)planeA, Wfrag, wlf, gcur, cap, n4);

  // CSR build
  bucketA_k<<<(E + 2047) / 2048, 256, 0, stream>>>(src, dstp, gcur, coarse, E, NC);
  bucketB_k<<<NC, 256, 0, stream>>>(gcur, coarse, cap, esrc, offsets, inv_cnt, N, NC);

  const int aggGrid = (N * 16 + 255) / 256;   // 16 threads per node
  const int ntiles = (N + 31) / 32;
  const int sageGrid = 1024;                  // grid-stride ~3 tiles/block

  // layer 1
  aggregate_k<<<aggGrid, 256, 0, stream>>>(planeA, offsets, esrc, inv_cnt, aggh, N);
  sage_layer_mfma_k<false><<<sageGrid, 256, 0, stream>>>(
      planeA, aggh, Wfrag + 0 * 65536, bl + 0 * D, planeB, wlf, blin, nullptr, N, ntiles);
  // layer 2
  aggregate_k<<<aggGrid, 256, 0, stream>>>(planeB, offsets, esrc, inv_cnt, aggh, N);
  sage_layer_mfma_k<false><<<sageGrid, 256, 0, stream>>>(
      planeB, aggh, Wfrag + 1 * 65536, bl + 1 * D, planeA, wlf, blin, nullptr, N, ntiles);
  // layer 3 + fused final linear
  aggregate_k<<<aggGrid, 256, 0, stream>>>(planeA, offsets, esrc, inv_cnt, aggh, N);
  sage_layer_mfma_k<true><<<sageGrid, 256, 0, stream>>>(
      planeA, aggh, Wfrag + 2 * 65536, bl + 2 * D, nullptr, wlf, blin,
      (float*)d_out, N, ntiles);
}